// Round 11
// baseline (327.762 us; speedup 1.0000x reference)
//
#include <hip/hip_runtime.h>

typedef __attribute__((ext_vector_type(8))) _Float16 f16x8;
typedef __attribute__((ext_vector_type(4))) float    f32x4;
typedef __attribute__((ext_vector_type(4))) int      i32x4;

#define IN_F   4096
#define OUT_F  4096
#define NGRP   32
#define NKT    64          /* K-tiles of 64 */

#define GLOAD16(gsrc, ldst)                                                   \
    __builtin_amdgcn_global_load_lds(                                         \
        (const __attribute__((address_space(1))) unsigned int*)(gsrc),        \
        (__attribute__((address_space(3))) unsigned int*)(ldst), 16, 0, 0)

#define CFENCE  asm volatile("" ::: "memory")
#define BARRIER do { CFENCE; __builtin_amdgcn_s_barrier(); CFENCE; } while (0)
#define VMW4    asm volatile("s_waitcnt vmcnt(4)" ::: "memory")

// ---------------- fused prepass: X fp32->f16 and int4 dequant->f16 ----------
__global__ __launch_bounds__(256)
void prep(const float* __restrict__ X, const int* __restrict__ QW,
          const float* __restrict__ S, _Float16* __restrict__ XF,
          _Float16* __restrict__ WF) {
    if (blockIdx.x < 8192) {
        size_t i = ((size_t)blockIdx.x * 256 + threadIdx.x) * 8;
        f32x4 a = *(const f32x4*)(X + i);
        f32x4 b = *(const f32x4*)(X + i + 4);
        f16x8 h;
        h[0] = (_Float16)a[0]; h[1] = (_Float16)a[1];
        h[2] = (_Float16)a[2]; h[3] = (_Float16)a[3];
        h[4] = (_Float16)b[0]; h[5] = (_Float16)b[1];
        h[6] = (_Float16)b[2]; h[7] = (_Float16)b[3];
        *(f16x8*)(XF + i) = h;
    } else {
        size_t t  = ((size_t)blockIdx.x - 8192) * 256 + threadIdx.x;
        size_t jj = t * 4;                   // int32 index; 2048 per row
        size_t o  = jj >> 11;
        size_t jr = jj & 2047;
        const float s = S[o * NGRP + (jr >> 6)];   // group const across 4 int32
        i32x4 q = *(const i32x4*)(QW + jj);
        f16x8 h;
#pragma unroll
        for (int j = 0; j < 4; ++j) {
            const int v = q[j];
            h[2 * j]     = (_Float16)((float)(((v >> 4) & 15) - 8) * s);
            h[2 * j + 1] = (_Float16)((float)((v & 15) - 8) * s);
        }
        *(f16x8*)(WF + jj * 2) = h;
    }
}

// --------- main GEMM: 256^2, BK=64, A direct-from-global, B in LDS ----------
// A-frags (X, L2/L3-resident) load global->VGPR: 16 dwordx4/wave/tile; the
// 4x cross-wave redundancy hits L1/L2. LDS holds ONLY B: 3-buffer ring
// (3 x 32 KB), ds_reads drop 24->8 per wave per K-tile (LDS floor 61->20us).
// ONE barrier per K-tile. vmcnt ledger (in-order retirement): per tile issue
// [A x16, stageB(t+2) x4] -- stage is YOUNGER than all A, so per-use A-waits
// (vmcnt(4) max) never force-drain it; it drains during t+1's A-waits
// (>=1 tile lead, landed) and t+1's end barrier publishes it before t+2's
// reads. WAR: buf[(t+2)%3] last read at t-1, >=1 barrier before stage. VMW4
// at tile end is then a no-op safety; barrier publishes t+1 (each wave's own
// A-waits drained its t+1 DMAs during this tile).
__global__ __launch_bounds__(512, 2)
void gemm_ad(const _Float16* __restrict__ A,
             const _Float16* __restrict__ B,
             float*          __restrict__ C)
{
    extern __shared__ char ldsB[];      // 3 * 32768 = 96 KB

    const int tid  = threadIdx.x;
    const int lane = tid & 63;
    const int wid  = tid >> 6;
    const int wm   = wid >> 2;          // 0..1 -> M half (128 rows)
    const int wn   = wid & 3;           // 0..3 -> N quarter (64 cols)

    const int bid = blockIdx.x;         // 256 blocks, %8==0
    const int swz = (bid & 7) * 32 + (bid >> 3);
    const int bm0 = (swz >> 4) * 256;
    const int bn0 = (swz & 15) * 256;

    // B staging source: thread covers rows r0 + j*64, 16 B at swizzled col
    const int r0 = tid >> 3;                                // 0..63
    const int cs = ((tid & 7) * 16) ^ ((r0 & 7) << 4);      // involution
    const _Float16* Bsrc = B + (size_t)(bn0 + r0) * IN_F + (cs >> 1);
    const int dstoff = wid * 1024;                          // wave-uniform

    // B frag-read offsets (swizzled)
    const int lane15 = lane & 15;
    const int swr = (lane & 7) << 4;
    const int c0 = ((lane >> 4) * 16) ^ swr;        // kk=0 byte col
    const int c1 = (64 + (lane >> 4) * 16) ^ swr;   // kk=1
    int rBoff[4];
#pragma unroll
    for (int nn = 0; nn < 4; ++nn) rBoff[nn] = (wn * 64 + nn * 16 + lane15) * 128;

    // A direct pointers: row = bm0 + wm*128 + m*16 + lane15, k base (lane>>4)*8
    const _Float16* Ap[8];
#pragma unroll
    for (int m = 0; m < 8; ++m)
        Ap[m] = A + (size_t)(bm0 + wm * 128 + m * 16 + lane15) * IN_F
                  + (lane >> 4) * 8;

    f16x8 a[8][2], b[4][2];
    f32x4 acc[8][4];
#pragma unroll
    for (int m = 0; m < 8; ++m)
#pragma unroll
        for (int n = 0; n < 4; ++n) acc[m][n] = (f32x4)0.0f;

#define STAGE_B(KT, BUF) do {                                                 \
        _Pragma("unroll") for (int j = 0; j < 4; ++j)                         \
            GLOAD16(Bsrc + (size_t)j * 64 * IN_F + (KT) * 64,                 \
                    ldsB + (BUF) * 32768 + dstoff + j * 8192); } while (0)

    // prologue: tiles 0,1 -> buf0,buf1; retire tile0 (keep tile1 in flight)
    STAGE_B(0, 0); STAGE_B(1, 1);
    VMW4; BARRIER;

    int cur = 0;                        // t % 3
    for (int t = 0; t < NKT; ++t) {
        const int nx2 = (cur == 0) ? 2 : cur - 1;   // (t+2) % 3
        // ---- A loads (all 16, oldest in queue) ----
#pragma unroll
        for (int m = 0; m < 8; ++m) {
            const _Float16* ap = Ap[m] + t * 64;
            a[m][0] = *(const f16x8*)(ap);
            a[m][1] = *(const f16x8*)(ap + 32);
        }
        CFENCE;
        // ---- stage B(t+2) (youngest: A-waits never force-drain it) ----
        STAGE_B((t + 2) & 63, nx2);     // t>=62: dead restage, uniform counts
        CFENCE;
        // ---- B frags from LDS ----
        {
            char* bb = ldsB + cur * 32768;
#pragma unroll
            for (int nn = 0; nn < 4; ++nn) {
                b[nn][0] = *(const f16x8*)(bb + rBoff[nn] + c0);
                b[nn][1] = *(const f16x8*)(bb + rBoff[nn] + c1);
            }
        }
        // ---- 64 MFMA (m-major: a[m] consumption matches issue order) ----
        __builtin_amdgcn_s_setprio(1);
#pragma unroll
        for (int m = 0; m < 8; ++m)
#pragma unroll
            for (int nn = 0; nn < 4; ++nn)
#pragma unroll
                for (int kk = 0; kk < 2; ++kk)
                    acc[m][nn] = __builtin_amdgcn_mfma_f32_16x16x32_f16(
                        a[m][kk], b[nn][kk], acc[m][nn], 0, 0, 0);
        __builtin_amdgcn_s_setprio(0);
        VMW4; BARRIER;                  // publish t+1 (drained by A-waits)
        cur = (cur == 2) ? 0 : cur + 1;
    }
    asm volatile("s_waitcnt vmcnt(0)" ::: "memory");   // drain dead stages

#pragma unroll
    for (int m = 0; m < 8; ++m) {
        const int Mr = bm0 + wm * 128 + m * 16 + (lane >> 4) * 4;
#pragma unroll
        for (int nn = 0; nn < 4; ++nn) {
            const int Nc = bn0 + wn * 64 + nn * 16 + lane15;
#pragma unroll
            for (int r = 0; r < 4; ++r)
                C[(size_t)(Mr + r) * OUT_F + Nc] = acc[m][nn][r];
        }
    }
#undef STAGE_B
}

// ---------------- fallback: m97-structure GEMM (static 16 KB LDS) ----------
__global__ __launch_bounds__(256, 3)
void gemm_f16(const _Float16* __restrict__ A,
              const _Float16* __restrict__ B,
              float*          __restrict__ C)
{
    __shared__ __align__(16) _Float16 lA[128 * 32];
    __shared__ __align__(16) _Float16 lB[128 * 32];

    const int tid  = threadIdx.x;
    const int lane = tid & 63;
    const int bid = blockIdx.x;
    const int swz = (bid & 7) * 128 + (bid >> 3);
    const int bm0 = (swz >> 5) * 128;
    const int bn0 = (swz & 31) * 128;

    const int sr = tid >> 2;
    const int sc = (tid & 3) * 8;
    const _Float16* Aps = A + (size_t)(bm0 + sr) * IN_F + sc;
    const _Float16* Bps = B + (size_t)(bn0 + sr) * IN_F + sc;
    char* lAb = (char*)lA + (tid & ~63) * 16;
    char* lBb = (char*)lB + (tid & ~63) * 16;

    const int wv = tid >> 6;
    const int wr = (wv >> 1) * 64;
    const int wc = (wv & 1)  * 64;
    const int lr  = lane & 15;
    const int lkb = (lane >> 4) * 16;

    f32x4 acc[4][4];
#pragma unroll
    for (int m = 0; m < 4; ++m)
#pragma unroll
        for (int n = 0; n < 4; ++n) acc[m][n] = (f32x4)0.0f;

    for (int kt = 0; kt < 128; ++kt) {
        __syncthreads();
        {
            const _Float16* ak = Aps + kt * 32;
            const _Float16* bk = Bps + kt * 32;
            GLOAD16(ak, lAb);
            GLOAD16(ak + (size_t)64 * IN_F, lAb + 4096);
            GLOAD16(bk, lBb);
            GLOAD16(bk + (size_t)64 * IN_F, lBb + 4096);
        }
        __syncthreads();

        f16x8 a[4], b[4];
#pragma unroll
        for (int m = 0; m < 4; ++m)
            a[m] = *(const f16x8*)((const char*)lA + (wr + m * 16 + lr) * 64 + lkb);
#pragma unroll
        for (int n = 0; n < 4; ++n)
            b[n] = *(const f16x8*)((const char*)lB + (wc + n * 16 + lr) * 64 + lkb);
#pragma unroll
        for (int m = 0; m < 4; ++m)
#pragma unroll
            for (int n = 0; n < 4; ++n)
                acc[m][n] = __builtin_amdgcn_mfma_f32_16x16x32_f16(
                    a[m], b[n], acc[m][n], 0, 0, 0);
    }

    const int crow = bm0 + wr + (lane >> 4) * 4;
    const int ccol = bn0 + wc + lr;
#pragma unroll
    for (int m = 0; m < 4; ++m)
#pragma unroll
        for (int n = 0; n < 4; ++n)
#pragma unroll
            for (int r = 0; r < 4; ++r)
                C[(size_t)(crow + m * 16 + r) * OUT_F + (ccol + n * 16)]
                    = acc[m][n][r];
}

extern "C" void kernel_launch(void* const* d_in, const int* in_sizes, int n_in,
                              void* d_out, int out_size, void* d_ws, size_t ws_size,
                              hipStream_t stream) {
    (void)in_sizes; (void)n_in; (void)out_size; (void)ws_size;
    const float* x  = (const float*)d_in[0];
    const int*   qw = (const int*)d_in[1];
    const float* s  = (const float*)d_in[2];
    float*       out = (float*)d_out;

    _Float16* xf = (_Float16*)d_ws;
    _Float16* wf = xf + (size_t)OUT_F * IN_F;
    prep<<<dim3(16384), dim3(256), 0, stream>>>(x, qw, s, xf, wf);

    hipError_t e = hipFuncSetAttribute((const void*)gemm_ad,
        hipFuncAttributeMaxDynamicSharedMemorySize, 98304);
    if (e == hipSuccess)
        gemm_ad<<<dim3(256), dim3(512), 98304, stream>>>(xf, wf, out);
    else
        gemm_f16<<<dim3(1024), dim3(256), 0, stream>>>(xf, wf, out);
}

// Round 12
// 259.374 us; speedup vs baseline: 1.2637x; 1.2637x over previous
//
#include <hip/hip_runtime.h>

typedef __attribute__((ext_vector_type(8))) _Float16 f16x8;
typedef __attribute__((ext_vector_type(4))) float    f32x4;
typedef __attribute__((ext_vector_type(4))) int      i32x4;

#define IN_F   4096
#define OUT_F  4096
#define NGRP   32

#define GLOAD16(gsrc, ldst)                                                   \
    __builtin_amdgcn_global_load_lds(                                         \
        (const __attribute__((address_space(1))) unsigned int*)(gsrc),        \
        (__attribute__((address_space(3))) unsigned int*)(ldst), 16, 0, 0)

#define CFENCE  asm volatile("" ::: "memory")
#define BARRIER do { CFENCE; __builtin_amdgcn_s_barrier(); CFENCE; } while (0)
#define VMW6    asm volatile("s_waitcnt vmcnt(6)" ::: "memory")

// ---------------- fused prepass: X fp32->f16 and int4 dequant->f16 ----------
__global__ __launch_bounds__(256)
void prep(const float* __restrict__ X, const int* __restrict__ QW,
          const float* __restrict__ S, _Float16* __restrict__ XF,
          _Float16* __restrict__ WF) {
    if (blockIdx.x < 8192) {
        size_t i = ((size_t)blockIdx.x * 256 + threadIdx.x) * 8;
        f32x4 a = *(const f32x4*)(X + i);
        f32x4 b = *(const f32x4*)(X + i + 4);
        f16x8 h;
        h[0] = (_Float16)a[0]; h[1] = (_Float16)a[1];
        h[2] = (_Float16)a[2]; h[3] = (_Float16)a[3];
        h[4] = (_Float16)b[0]; h[5] = (_Float16)b[1];
        h[6] = (_Float16)b[2]; h[7] = (_Float16)b[3];
        *(f16x8*)(XF + i) = h;
    } else {
        size_t t  = ((size_t)blockIdx.x - 8192) * 256 + threadIdx.x;
        size_t jj = t * 4;                   // int32 index; 2048 per row
        size_t o  = jj >> 11;
        size_t jr = jj & 2047;
        const float s = S[o * NGRP + (jr >> 6)];   // group const across 4 int32
        i32x4 q = *(const i32x4*)(QW + jj);
        f16x8 h;
#pragma unroll
        for (int j = 0; j < 4; ++j) {
            const int v = q[j];
            h[2 * j]     = (_Float16)((float)(((v >> 4) & 15) - 8) * s);
            h[2 * j + 1] = (_Float16)((float)((v & 15) - 8) * s);
        }
        *(f16x8*)(WF + jj * 2) = h;
    }
}

// ------- main GEMM: 256x128 tile, 4 waves, BK=32, 3-ring LDS, 2 blocks/CU ---
// Mechanism: 72 KB LDS + ~252 reg/wave -> TWO independent blocks per CU; each
// SIMD hosts 2 waves with INDEPENDENT barriers, so one block's sync/latency
// stalls overlap the other's MFMA (m97's TLP mechanism at 256-class tiles).
// LDS layout [ks][row] (word = ks*R + row, 16B words): frag reads are 16
// consecutive words -> conflict-free; layout is linear in gload_lds DMA
// order by construction (no swizzle needed).
// Ledger per K-tile t: read ring[t%3]; stage(t+2)->ring[(t+2)%3]; MFMA;
// VMW6 (<=12 outstanding -> retire stage t+1, keep t+2); BARRIER publishes.
// WAR: ring[(t+2)%3] last read at t-1, >=1 barrier before the stage.
__global__ __launch_bounds__(256, 2)
void gemm_tlp(const _Float16* __restrict__ A,
              const _Float16* __restrict__ B,
              float*          __restrict__ C)
{
    extern __shared__ char LDSc[];
    char* const ldsA = LDSc;            // 3 * 16384
    char* const ldsB = LDSc + 49152;    // 3 * 8192

    const int tid  = threadIdx.x;
    const int lane = tid & 63;
    const int wid  = tid >> 6;          // 0..3
    const int wm   = wid >> 1;          // 0..1 -> M half (128 rows)
    const int wn   = wid & 1;           // 0..1 -> N half (64 cols)

    const int bid = blockIdx.x;         // 512 blocks (16 M x 32 N), %8==0
    const int swz = (bid & 7) * 64 + (bid >> 3);
    const int bm0 = (swz >> 5) * 256;
    const int bn0 = (swz & 31) * 128;

    // staging sources: A thread -> row tid (4 ks-chunks of its row);
    // B thread -> row tid&127, ks-base tid>>7 (2 chunks)
    const _Float16* Asrc = A + (size_t)(bm0 + tid) * IN_F;
    const _Float16* Bsrc = B + (size_t)(bn0 + (tid & 127)) * IN_F + (tid >> 7) * 8;
    const int dstoff = wid * 1024;      // wave-uniform; dest word = chunk*256 + tid

    // frag-read byte offsets: word = ks*R + row  (ks = lane>>4)
    const int lane15 = lane & 15;
    const int ks     = lane >> 4;
    int aoff[8], boff[4];
#pragma unroll
    for (int m = 0; m < 8; ++m)
        aoff[m] = (ks * 256 + wm * 128 + m * 16 + lane15) * 16;
#pragma unroll
    for (int n = 0; n < 4; ++n)
        boff[n] = (ks * 128 + wn * 64 + n * 16 + lane15) * 16;

    f16x8 a[8], b[4];
    f32x4 acc[8][4];
#pragma unroll
    for (int m = 0; m < 8; ++m)
#pragma unroll
        for (int n = 0; n < 4; ++n) acc[m][n] = (f32x4)0.0f;

#define STAGE(KT, R) do {                                                     \
        _Pragma("unroll") for (int c = 0; c < 4; ++c)                         \
            GLOAD16(Asrc + (KT) * 32 + c * 8,                                 \
                    ldsA + (R) * 16384 + c * 4096 + dstoff);                  \
        _Pragma("unroll") for (int c = 0; c < 2; ++c)                         \
            GLOAD16(Bsrc + (KT) * 32 + c * 16,                                \
                    ldsB + (R) * 8192 + c * 4096 + dstoff); } while (0)

    // prologue: tiles 0,1 -> rings 0,1 (12 loads); VMW6 retires tile0
    STAGE(0, 0); STAGE(1, 1);
    VMW6; BARRIER;

    int r0 = 0;
    for (int t = 0; t < 128; ++t) {
        int r2 = r0 + 2; if (r2 >= 3) r2 -= 3;
        char* ab = ldsA + r0 * 16384;
        char* bb = ldsB + r0 * 8192;
#pragma unroll
        for (int m = 0; m < 8; ++m) a[m] = *(const f16x8*)(ab + aoff[m]);
#pragma unroll
        for (int n = 0; n < 4; ++n) b[n] = *(const f16x8*)(bb + boff[n]);
        STAGE((t + 2) & 127, r2);       // t>=126: dead restage, uniform counts
        __builtin_amdgcn_s_setprio(1);
#pragma unroll
        for (int m = 0; m < 8; ++m)
#pragma unroll
            for (int n = 0; n < 4; ++n)
                acc[m][n] = __builtin_amdgcn_mfma_f32_16x16x32_f16(
                    a[m], b[n], acc[m][n], 0, 0, 0);
        __builtin_amdgcn_s_setprio(0);
        VMW6; BARRIER;                  // retire t+1, publish; keep t+2 in flight
        r0 = (r0 == 2) ? 0 : r0 + 1;
    }
    asm volatile("s_waitcnt vmcnt(0)" ::: "memory");   // drain dead stages

#pragma unroll
    for (int m = 0; m < 8; ++m) {
        const int Mr = bm0 + wm * 128 + m * 16 + ks * 4;
#pragma unroll
        for (int n = 0; n < 4; ++n) {
            const int Nc = bn0 + wn * 64 + n * 16 + lane15;
#pragma unroll
            for (int r = 0; r < 4; ++r)
                C[(size_t)(Mr + r) * OUT_F + Nc] = acc[m][n][r];
        }
    }
#undef STAGE
}

// ---------------- fallback 1: round-10 merged-phase 256^2 kernel ------------
__global__ __launch_bounds__(512, 2)
void gemm8p(const _Float16* __restrict__ A,
            const _Float16* __restrict__ B,
            float*          __restrict__ C)
{
    extern __shared__ char LDSc[];
    char* const ldsA = LDSc;
    char* const ldsB = LDSc + 65536;

    const int tid  = threadIdx.x;
    const int lane = tid & 63;
    const int wid  = tid >> 6;
    const int wm   = wid >> 2;
    const int wn   = wid & 3;

    const int bid = blockIdx.x;
    const int swz = (bid & 7) * 32 + (bid >> 3);
    const int bm0 = (swz >> 4) * 256;
    const int bn0 = (swz & 15) * 256;

    const int r0 = tid >> 3;
    const int cs = ((tid & 7) * 16) ^ ((r0 & 7) << 4);
    const _Float16* Asrc = A + (size_t)(bm0 + r0) * IN_F + (cs >> 1);
    const _Float16* Bsrc = B + (size_t)(bn0 + r0) * IN_F + (cs >> 1);
    const int dstoff = wid * 1024;

    const int lane15 = lane & 15;
    const int swr = (lane & 7) << 4;
    const int c0 = ((lane >> 4) * 16) ^ swr;
    const int c1 = (64 + (lane >> 4) * 16) ^ swr;
    int rAoff[4], rBoff[2];
#pragma unroll
    for (int mm = 0; mm < 4; ++mm) rAoff[mm] = (wm * 64 + mm * 16 + lane15) * 128;
#pragma unroll
    for (int nn = 0; nn < 2; ++nn) rBoff[nn] = (wn * 32 + nn * 16 + lane15) * 128;

    f16x8 afr[4][2], blo[2][2], bhi[2][2];
    f32x4 acc[8][4];
#pragma unroll
    for (int m = 0; m < 8; ++m)
#pragma unroll
        for (int n = 0; n < 4; ++n) acc[m][n] = (f32x4)0.0f;

#define STAGE_A(HALF, KT, BUF) do {                                           \
        const _Float16* s_ = Asrc + (size_t)(HALF) * 128 * IN_F + (KT) * 64;  \
        char* d_ = ldsA + ((BUF) * 2 + (HALF)) * 16384 + dstoff;              \
        GLOAD16(s_, d_);                                                      \
        GLOAD16(s_ + (size_t)64 * IN_F, d_ + 8192); } while (0)

#define STAGE_B(HALF, KT, BUF) do {                                           \
        const _Float16* s_ = Bsrc + (size_t)(HALF) * 128 * IN_F + (KT) * 64;  \
        char* d_ = ldsB + ((BUF) * 2 + (HALF)) * 16384 + dstoff;              \
        GLOAD16(s_, d_);                                                      \
        GLOAD16(s_ + (size_t)64 * IN_F, d_ + 8192); } while (0)

#define RD_A(BUF, QM) do { char* ab_ = ldsA + ((BUF) * 2 + (QM)) * 16384;     \
        _Pragma("unroll") for (int mm = 0; mm < 4; ++mm) {                    \
            afr[mm][0] = *(const f16x8*)(ab_ + rAoff[mm] + c0);               \
            afr[mm][1] = *(const f16x8*)(ab_ + rAoff[mm] + c1); } } while (0)

#define RD_B(BUF, QN, DST) do { char* bb_ = ldsB + ((BUF) * 2 + (QN)) * 16384;\
        _Pragma("unroll") for (int nn = 0; nn < 2; ++nn) {                    \
            DST[nn][0] = *(const f16x8*)(bb_ + rBoff[nn] + c0);               \
            DST[nn][1] = *(const f16x8*)(bb_ + rBoff[nn] + c1); } } while (0)

#define MFMA_Q(QM, QN, BQ)                                                    \
        __builtin_amdgcn_s_setprio(1);                                        \
        _Pragma("unroll") for (int mm = 0; mm < 4; ++mm)                      \
        _Pragma("unroll") for (int nn = 0; nn < 2; ++nn)                      \
        _Pragma("unroll") for (int kk = 0; kk < 2; ++kk)                      \
            acc[(QM)*4+mm][(QN)*2+nn] =                                       \
                __builtin_amdgcn_mfma_f32_16x16x32_f16(                       \
                    afr[mm][kk], BQ[nn][kk], acc[(QM)*4+mm][(QN)*2+nn],0,0,0);\
        __builtin_amdgcn_s_setprio(0);

    STAGE_A(0, 0, 0); STAGE_B(0, 0, 0); STAGE_B(1, 0, 0); STAGE_A(1, 0, 0);
    STAGE_A(0, 1, 1); STAGE_B(0, 1, 1); STAGE_B(1, 1, 1);
    VMW6; BARRIER;

    for (int t = 0; t < 64; t += 2) {
        const int k2 = (t + 2) & 63;
        const int k3 = (t + 3) & 63;
        RD_A(0, 0); RD_B(0, 0, blo); RD_B(0, 1, bhi);
        STAGE_A(1, t + 1, 1);
        MFMA_Q(0, 0, blo); MFMA_Q(0, 1, bhi);
        BARRIER;
        RD_A(0, 1);
        STAGE_A(0, k2, 0); STAGE_B(0, k2, 0); STAGE_B(1, k2, 0);
        MFMA_Q(1, 0, blo); MFMA_Q(1, 1, bhi);
        VMW6; BARRIER;
        RD_A(1, 0); RD_B(1, 0, blo); RD_B(1, 1, bhi);
        STAGE_A(1, k2, 0);
        MFMA_Q(0, 0, blo); MFMA_Q(0, 1, bhi);
        BARRIER;
        RD_A(1, 1);
        STAGE_A(0, k3, 1); STAGE_B(0, k3, 1); STAGE_B(1, k3, 1);
        MFMA_Q(1, 0, blo); MFMA_Q(1, 1, bhi);
        VMW6; BARRIER;
    }
    asm volatile("s_waitcnt vmcnt(0)" ::: "memory");

#pragma unroll
    for (int m = 0; m < 8; ++m) {
        const int Mr = bm0 + (m >> 2) * 128 + wm * 64 + (m & 3) * 16 + (lane >> 4) * 4;
#pragma unroll
        for (int n = 0; n < 4; ++n) {
            const int Nc = bn0 + (n >> 1) * 128 + wn * 32 + (n & 1) * 16 + lane15;
#pragma unroll
            for (int r = 0; r < 4; ++r)
                C[(size_t)(Mr + r) * OUT_F + Nc] = acc[m][n][r];
        }
    }
#undef STAGE_A
#undef STAGE_B
#undef RD_A
#undef RD_B
#undef MFMA_Q
}

// ---------------- fallback 2: m97-structure GEMM (static 16 KB LDS) ---------
__global__ __launch_bounds__(256, 3)
void gemm_f16(const _Float16* __restrict__ A,
              const _Float16* __restrict__ B,
              float*          __restrict__ C)
{
    __shared__ __align__(16) _Float16 lA[128 * 32];
    __shared__ __align__(16) _Float16 lB[128 * 32];

    const int tid  = threadIdx.x;
    const int lane = tid & 63;
    const int bid = blockIdx.x;
    const int swz = (bid & 7) * 128 + (bid >> 3);
    const int bm0 = (swz >> 5) * 128;
    const int bn0 = (swz & 31) * 128;

    const int sr = tid >> 2;
    const int sc = (tid & 3) * 8;
    const _Float16* Aps = A + (size_t)(bm0 + sr) * IN_F + sc;
    const _Float16* Bps = B + (size_t)(bn0 + sr) * IN_F + sc;
    char* lAb = (char*)lA + (tid & ~63) * 16;
    char* lBb = (char*)lB + (tid & ~63) * 16;

    const int wv = tid >> 6;
    const int wr = (wv >> 1) * 64;
    const int wc = (wv & 1)  * 64;
    const int lr  = lane & 15;
    const int lkb = (lane >> 4) * 16;

    f32x4 acc[4][4];
#pragma unroll
    for (int m = 0; m < 4; ++m)
#pragma unroll
        for (int n = 0; n < 4; ++n) acc[m][n] = (f32x4)0.0f;

    for (int kt = 0; kt < 128; ++kt) {
        __syncthreads();
        {
            const _Float16* ak = Aps + kt * 32;
            const _Float16* bk = Bps + kt * 32;
            GLOAD16(ak, lAb);
            GLOAD16(ak + (size_t)64 * IN_F, lAb + 4096);
            GLOAD16(bk, lBb);
            GLOAD16(bk + (size_t)64 * IN_F, lBb + 4096);
        }
        __syncthreads();

        f16x8 a[4], b[4];
#pragma unroll
        for (int m = 0; m < 4; ++m)
            a[m] = *(const f16x8*)((const char*)lA + (wr + m * 16 + lr) * 64 + lkb);
#pragma unroll
        for (int n = 0; n < 4; ++n)
            b[n] = *(const f16x8*)((const char*)lB + (wc + n * 16 + lr) * 64 + lkb);
#pragma unroll
        for (int m = 0; m < 4; ++m)
#pragma unroll
            for (int n = 0; n < 4; ++n)
                acc[m][n] = __builtin_amdgcn_mfma_f32_16x16x32_f16(
                    a[m], b[n], acc[m][n], 0, 0, 0);
    }

    const int crow = bm0 + wr + (lane >> 4) * 4;
    const int ccol = bn0 + wc + lr;
#pragma unroll
    for (int m = 0; m < 4; ++m)
#pragma unroll
        for (int n = 0; n < 4; ++n)
#pragma unroll
            for (int r = 0; r < 4; ++r)
                C[(size_t)(crow + m * 16 + r) * OUT_F + (ccol + n * 16)]
                    = acc[m][n][r];
}

extern "C" void kernel_launch(void* const* d_in, const int* in_sizes, int n_in,
                              void* d_out, int out_size, void* d_ws, size_t ws_size,
                              hipStream_t stream) {
    (void)in_sizes; (void)n_in; (void)out_size; (void)ws_size;
    const float* x  = (const float*)d_in[0];
    const int*   qw = (const int*)d_in[1];
    const float* s  = (const float*)d_in[2];
    float*       out = (float*)d_out;

    _Float16* xf = (_Float16*)d_ws;
    _Float16* wf = xf + (size_t)OUT_F * IN_F;
    prep<<<dim3(16384), dim3(256), 0, stream>>>(x, qw, s, xf, wf);

    hipError_t e1 = hipFuncSetAttribute((const void*)gemm_tlp,
        hipFuncAttributeMaxDynamicSharedMemorySize, 73728);
    if (e1 == hipSuccess) {
        gemm_tlp<<<dim3(512), dim3(256), 73728, stream>>>(xf, wf, out);
        return;
    }
    hipError_t e2 = hipFuncSetAttribute((const void*)gemm8p,
        hipFuncAttributeMaxDynamicSharedMemorySize, 131072);
    if (e2 == hipSuccess)
        gemm8p<<<dim3(256), dim3(512), 131072, stream>>>(xf, wf, out);
    else
        gemm_f16<<<dim3(1024), dim3(256), 0, stream>>>(xf, wf, out);
}

// Round 13
// 149.248 us; speedup vs baseline: 2.1961x; 1.7379x over previous
//
#include <hip/hip_runtime.h>

typedef __attribute__((ext_vector_type(8))) _Float16 f16x8;
typedef __attribute__((ext_vector_type(4))) float    f32x4;
typedef __attribute__((ext_vector_type(4))) int      i32x4;

#define IN_F   4096
#define OUT_F  4096
#define NGRP   32

#define GLOAD16(gsrc, ldst)                                                   \
    __builtin_amdgcn_global_load_lds(                                         \
        (const __attribute__((address_space(1))) unsigned int*)(gsrc),        \
        (__attribute__((address_space(3))) unsigned int*)(ldst), 16, 0, 0)

#define CFENCE  asm volatile("" ::: "memory")
#define BARRIER do { CFENCE; __builtin_amdgcn_s_barrier(); CFENCE; } while (0)
#define VMW4    asm volatile("s_waitcnt vmcnt(4)" ::: "memory")
#define VMW6    asm volatile("s_waitcnt vmcnt(6)" ::: "memory")

// ---------------- fused prepass: X fp32->f16 and int4 dequant->f16 ----------
__global__ __launch_bounds__(256)
void prep(const float* __restrict__ X, const int* __restrict__ QW,
          const float* __restrict__ S, _Float16* __restrict__ XF,
          _Float16* __restrict__ WF) {
    if (blockIdx.x < 8192) {
        size_t i = ((size_t)blockIdx.x * 256 + threadIdx.x) * 8;
        f32x4 a = *(const f32x4*)(X + i);
        f32x4 b = *(const f32x4*)(X + i + 4);
        f16x8 h;
        h[0] = (_Float16)a[0]; h[1] = (_Float16)a[1];
        h[2] = (_Float16)a[2]; h[3] = (_Float16)a[3];
        h[4] = (_Float16)b[0]; h[5] = (_Float16)b[1];
        h[6] = (_Float16)b[2]; h[7] = (_Float16)b[3];
        *(f16x8*)(XF + i) = h;
    } else {
        size_t t  = ((size_t)blockIdx.x - 8192) * 256 + threadIdx.x;
        size_t jj = t * 4;                   // int32 index; 2048 per row
        size_t o  = jj >> 11;
        size_t jr = jj & 2047;
        const float s = S[o * NGRP + (jr >> 6)];   // group const across 4 int32
        i32x4 q = *(const i32x4*)(QW + jj);
        f16x8 h;
#pragma unroll
        for (int j = 0; j < 4; ++j) {
            const int v = q[j];
            h[2 * j]     = (_Float16)((float)(((v >> 4) & 15) - 8) * s);
            h[2 * j + 1] = (_Float16)((float)((v & 15) - 8) * s);
        }
        *(f16x8*)(WF + jj * 2) = h;
    }
}

// ------ main GEMM: 256^2, BK=32, 3-slot LDS ring, FULL-TILE stage lead ------
// One phase per K-tile: {12 frag b128 reads (slot t%3) | stage tile t+2 ->
// slot (t+2)%3 | 32 MFMA} ; VMW4 ; BARRIER.
// Lead fix (r10's flaw): at VMW4, outstanding = t+1 (4 loads, issued a FULL
// tile ago ~2000cyc) + t+2 (4, this tile); retiring t+1 is a no-op wait --
// r10 waited on loads issued only ~550cyc earlier (1 phase) = hard stall.
// Staging keeps r10's coalescing: 4 consecutive lanes cover 64B of one row;
// DMA dest linear (dstoff=wid*1024 + lane*16 by HW), source pre-swizzled
// cs=(tid&3)*16 ^ ((row&3)<<4), frag reads apply the same XOR (rule 21).
// WAR: slot (t+2)%3 last read at t-1, >=1 barrier before the stage.
__global__ __launch_bounds__(512, 2)
void gemm_r3(const _Float16* __restrict__ A,
             const _Float16* __restrict__ B,
             float*          __restrict__ C)
{
    extern __shared__ char LDSc[];      // 3 slots x 32 KB (A 16K + B 16K)

    const int tid  = threadIdx.x;
    const int lane = tid & 63;
    const int wid  = tid >> 6;
    const int wm   = wid >> 2;          // 0..1 -> M half (128 rows)
    const int wn   = wid & 3;           // 0..3 -> N quarter (64 cols)

    const int bid = blockIdx.x;         // 256 blocks, %8==0
    const int swz = (bid & 7) * 32 + (bid >> 3);
    const int bm0 = (swz >> 4) * 256;
    const int bn0 = (swz & 15) * 256;

    // staging: thread -> rows tr and tr+128, 16B at pre-swizzled byte-col cs
    const int tr = tid >> 2;                                // 0..127
    const int cs = ((tid & 3) * 16) ^ ((tr & 3) << 4);      // involution in 64B row
    const _Float16* Asrc = A + (size_t)(bm0 + tr) * IN_F + (cs >> 1);
    const _Float16* Bsrc = B + (size_t)(bn0 + tr) * IN_F + (cs >> 1);
    const int dstoff = wid * 1024;                          // wave-uniform

    // frag-read byte offsets: row*64 + (ks*16 ^ ((row&3)<<4)), ks = lane>>4
    const int lane15 = lane & 15;
    const int ks     = lane >> 4;
    int aoff[8], boff[4];
#pragma unroll
    for (int m = 0; m < 8; ++m) {
        const int ar = wm * 128 + m * 16 + lane15;
        aoff[m] = ar * 64 + ((ks * 16) ^ ((ar & 3) << 4));
    }
#pragma unroll
    for (int n = 0; n < 4; ++n) {
        const int br = wn * 64 + n * 16 + lane15;
        boff[n] = br * 64 + ((ks * 16) ^ ((br & 3) << 4));
    }

    f16x8 a[8], b[4];
    f32x4 acc[8][4];
#pragma unroll
    for (int m = 0; m < 8; ++m)
#pragma unroll
        for (int n = 0; n < 4; ++n) acc[m][n] = (f32x4)0.0f;

#define STAGE(KT, SL) do {                                                    \
        char* d_ = LDSc + (SL) * 32768 + dstoff;                              \
        GLOAD16(Asrc + (KT) * 32, d_);                                        \
        GLOAD16(Asrc + (size_t)128 * IN_F + (KT) * 32, d_ + 8192);            \
        GLOAD16(Bsrc + (KT) * 32, d_ + 16384);                                \
        GLOAD16(Bsrc + (size_t)128 * IN_F + (KT) * 32, d_ + 24576); } while (0)

    // prologue: tiles 0,1 -> slots 0,1; retire tile0 (keep tile1 in flight)
    STAGE(0, 0); STAGE(1, 1);
    VMW4; BARRIER;

    int sl = 0;                         // t % 3
    for (int t = 0; t < 128; ++t) {
        const int s2 = (sl >= 1) ? sl - 1 : 2;     // (t+2) % 3
        char* base = LDSc + sl * 32768;
#pragma unroll
        for (int m = 0; m < 8; ++m) a[m] = *(const f16x8*)(base + aoff[m]);
#pragma unroll
        for (int n = 0; n < 4; ++n) b[n] = *(const f16x8*)(base + 16384 + boff[n]);
        STAGE((t + 2) & 127, s2);       // t>=126: dead restage, uniform counts
        __builtin_amdgcn_s_setprio(1);
#pragma unroll
        for (int m = 0; m < 8; ++m)
#pragma unroll
            for (int n = 0; n < 4; ++n)
                acc[m][n] = __builtin_amdgcn_mfma_f32_16x16x32_f16(
                    a[m], b[n], acc[m][n], 0, 0, 0);
        __builtin_amdgcn_s_setprio(0);
        VMW4; BARRIER;                  // retire t+1 (full-tile lead), publish
        sl = (sl == 2) ? 0 : sl + 1;
    }
    asm volatile("s_waitcnt vmcnt(0)" ::: "memory");   // drain dead stages

#pragma unroll
    for (int m = 0; m < 8; ++m) {
        const int Mr = bm0 + wm * 128 + m * 16 + ks * 4;
#pragma unroll
        for (int n = 0; n < 4; ++n) {
            const int Nc = bn0 + wn * 64 + n * 16 + lane15;
#pragma unroll
            for (int r = 0; r < 4; ++r)
                C[(size_t)(Mr + r) * OUT_F + Nc] = acc[m][n][r];
        }
    }
#undef STAGE
}

// ---------------- fallback 1: round-10 merged-phase 256^2 kernel ------------
__global__ __launch_bounds__(512, 2)
void gemm8p(const _Float16* __restrict__ A,
            const _Float16* __restrict__ B,
            float*          __restrict__ C)
{
    extern __shared__ char LDSc[];
    char* const ldsA = LDSc;
    char* const ldsB = LDSc + 65536;

    const int tid  = threadIdx.x;
    const int lane = tid & 63;
    const int wid  = tid >> 6;
    const int wm   = wid >> 2;
    const int wn   = wid & 3;

    const int bid = blockIdx.x;
    const int swz = (bid & 7) * 32 + (bid >> 3);
    const int bm0 = (swz >> 4) * 256;
    const int bn0 = (swz & 15) * 256;

    const int r0 = tid >> 3;
    const int cs = ((tid & 7) * 16) ^ ((r0 & 7) << 4);
    const _Float16* Asrc = A + (size_t)(bm0 + r0) * IN_F + (cs >> 1);
    const _Float16* Bsrc = B + (size_t)(bn0 + r0) * IN_F + (cs >> 1);
    const int dstoff = wid * 1024;

    const int lane15 = lane & 15;
    const int swr = (lane & 7) << 4;
    const int c0 = ((lane >> 4) * 16) ^ swr;
    const int c1 = (64 + (lane >> 4) * 16) ^ swr;
    int rAoff[4], rBoff[2];
#pragma unroll
    for (int mm = 0; mm < 4; ++mm) rAoff[mm] = (wm * 64 + mm * 16 + lane15) * 128;
#pragma unroll
    for (int nn = 0; nn < 2; ++nn) rBoff[nn] = (wn * 32 + nn * 16 + lane15) * 128;

    f16x8 afr[4][2], blo[2][2], bhi[2][2];
    f32x4 acc[8][4];
#pragma unroll
    for (int m = 0; m < 8; ++m)
#pragma unroll
        for (int n = 0; n < 4; ++n) acc[m][n] = (f32x4)0.0f;

#define STAGE_A(HALF, KT, BUF) do {                                           \
        const _Float16* s_ = Asrc + (size_t)(HALF) * 128 * IN_F + (KT) * 64;  \
        char* d_ = ldsA + ((BUF) * 2 + (HALF)) * 16384 + dstoff;              \
        GLOAD16(s_, d_);                                                      \
        GLOAD16(s_ + (size_t)64 * IN_F, d_ + 8192); } while (0)

#define STAGE_B(HALF, KT, BUF) do {                                           \
        const _Float16* s_ = Bsrc + (size_t)(HALF) * 128 * IN_F + (KT) * 64;  \
        char* d_ = ldsB + ((BUF) * 2 + (HALF)) * 16384 + dstoff;              \
        GLOAD16(s_, d_);                                                      \
        GLOAD16(s_ + (size_t)64 * IN_F, d_ + 8192); } while (0)

#define RD_A(BUF, QM) do { char* ab_ = ldsA + ((BUF) * 2 + (QM)) * 16384;     \
        _Pragma("unroll") for (int mm = 0; mm < 4; ++mm) {                    \
            afr[mm][0] = *(const f16x8*)(ab_ + rAoff[mm] + c0);               \
            afr[mm][1] = *(const f16x8*)(ab_ + rAoff[mm] + c1); } } while (0)

#define RD_B(BUF, QN, DST) do { char* bb_ = ldsB + ((BUF) * 2 + (QN)) * 16384;\
        _Pragma("unroll") for (int nn = 0; nn < 2; ++nn) {                    \
            DST[nn][0] = *(const f16x8*)(bb_ + rBoff[nn] + c0);               \
            DST[nn][1] = *(const f16x8*)(bb_ + rBoff[nn] + c1); } } while (0)

#define MFMA_Q(QM, QN, BQ)                                                    \
        __builtin_amdgcn_s_setprio(1);                                        \
        _Pragma("unroll") for (int mm = 0; mm < 4; ++mm)                      \
        _Pragma("unroll") for (int nn = 0; nn < 2; ++nn)                      \
        _Pragma("unroll") for (int kk = 0; kk < 2; ++kk)                      \
            acc[(QM)*4+mm][(QN)*2+nn] =                                       \
                __builtin_amdgcn_mfma_f32_16x16x32_f16(                       \
                    afr[mm][kk], BQ[nn][kk], acc[(QM)*4+mm][(QN)*2+nn],0,0,0);\
        __builtin_amdgcn_s_setprio(0);

    STAGE_A(0, 0, 0); STAGE_B(0, 0, 0); STAGE_B(1, 0, 0); STAGE_A(1, 0, 0);
    STAGE_A(0, 1, 1); STAGE_B(0, 1, 1); STAGE_B(1, 1, 1);
    VMW6; BARRIER;

    for (int t = 0; t < 64; t += 2) {
        const int k2 = (t + 2) & 63;
        const int k3 = (t + 3) & 63;
        RD_A(0, 0); RD_B(0, 0, blo); RD_B(0, 1, bhi);
        STAGE_A(1, t + 1, 1);
        MFMA_Q(0, 0, blo); MFMA_Q(0, 1, bhi);
        BARRIER;
        RD_A(0, 1);
        STAGE_A(0, k2, 0); STAGE_B(0, k2, 0); STAGE_B(1, k2, 0);
        MFMA_Q(1, 0, blo); MFMA_Q(1, 1, bhi);
        VMW6; BARRIER;
        RD_A(1, 0); RD_B(1, 0, blo); RD_B(1, 1, bhi);
        STAGE_A(1, k2, 0);
        MFMA_Q(0, 0, blo); MFMA_Q(0, 1, bhi);
        BARRIER;
        RD_A(1, 1);
        STAGE_A(0, k3, 1); STAGE_B(0, k3, 1); STAGE_B(1, k3, 1);
        MFMA_Q(1, 0, blo); MFMA_Q(1, 1, bhi);
        VMW6; BARRIER;
    }
    asm volatile("s_waitcnt vmcnt(0)" ::: "memory");

#pragma unroll
    for (int m = 0; m < 8; ++m) {
        const int Mr = bm0 + (m >> 2) * 128 + wm * 64 + (m & 3) * 16 + (lane >> 4) * 4;
#pragma unroll
        for (int n = 0; n < 4; ++n) {
            const int Nc = bn0 + (n >> 1) * 128 + wn * 32 + (n & 1) * 16 + lane15;
#pragma unroll
            for (int r = 0; r < 4; ++r)
                C[(size_t)(Mr + r) * OUT_F + Nc] = acc[m][n][r];
        }
    }
#undef STAGE_A
#undef STAGE_B
#undef RD_A
#undef RD_B
#undef MFMA_Q
}

// ---------------- fallback 2: m97-structure GEMM (static 16 KB LDS) ---------
__global__ __launch_bounds__(256, 3)
void gemm_f16(const _Float16* __restrict__ A,
              const _Float16* __restrict__ B,
              float*          __restrict__ C)
{
    __shared__ __align__(16) _Float16 lA[128 * 32];
    __shared__ __align__(16) _Float16 lB[128 * 32];

    const int tid  = threadIdx.x;
    const int lane = tid & 63;
    const int bid = blockIdx.x;
    const int swz = (bid & 7) * 128 + (bid >> 3);
    const int bm0 = (swz >> 5) * 128;
    const int bn0 = (swz & 31) * 128;

    const int sr = tid >> 2;
    const int sc = (tid & 3) * 8;
    const _Float16* Aps = A + (size_t)(bm0 + sr) * IN_F + sc;
    const _Float16* Bps = B + (size_t)(bn0 + sr) * IN_F + sc;
    char* lAb = (char*)lA + (tid & ~63) * 16;
    char* lBb = (char*)lB + (tid & ~63) * 16;

    const int wv = tid >> 6;
    const int wr = (wv >> 1) * 64;
    const int wc = (wv & 1)  * 64;
    const int lr  = lane & 15;
    const int lkb = (lane >> 4) * 16;

    f32x4 acc[4][4];
#pragma unroll
    for (int m = 0; m < 4; ++m)
#pragma unroll
        for (int n = 0; n < 4; ++n) acc[m][n] = (f32x4)0.0f;

    for (int kt = 0; kt < 128; ++kt) {
        __syncthreads();
        {
            const _Float16* ak = Aps + kt * 32;
            const _Float16* bk = Bps + kt * 32;
            GLOAD16(ak, lAb);
            GLOAD16(ak + (size_t)64 * IN_F, lAb + 4096);
            GLOAD16(bk, lBb);
            GLOAD16(bk + (size_t)64 * IN_F, lBb + 4096);
        }
        __syncthreads();

        f16x8 a[4], b[4];
#pragma unroll
        for (int m = 0; m < 4; ++m)
            a[m] = *(const f16x8*)((const char*)lA + (wr + m * 16 + lr) * 64 + lkb);
#pragma unroll
        for (int n = 0; n < 4; ++n)
            b[n] = *(const f16x8*)((const char*)lB + (wc + n * 16 + lr) * 64 + lkb);
#pragma unroll
        for (int m = 0; m < 4; ++m)
#pragma unroll
            for (int n = 0; n < 4; ++n)
                acc[m][n] = __builtin_amdgcn_mfma_f32_16x16x32_f16(
                    a[m], b[n], acc[m][n], 0, 0, 0);
    }

    const int crow = bm0 + wr + (lane >> 4) * 4;
    const int ccol = bn0 + wc + lr;
#pragma unroll
    for (int m = 0; m < 4; ++m)
#pragma unroll
        for (int n = 0; n < 4; ++n)
#pragma unroll
            for (int r = 0; r < 4; ++r)
                C[(size_t)(crow + m * 16 + r) * OUT_F + (ccol + n * 16)]
                    = acc[m][n][r];
}

extern "C" void kernel_launch(void* const* d_in, const int* in_sizes, int n_in,
                              void* d_out, int out_size, void* d_ws, size_t ws_size,
                              hipStream_t stream) {
    (void)in_sizes; (void)n_in; (void)out_size; (void)ws_size;
    const float* x  = (const float*)d_in[0];
    const int*   qw = (const int*)d_in[1];
    const float* s  = (const float*)d_in[2];
    float*       out = (float*)d_out;

    _Float16* xf = (_Float16*)d_ws;
    _Float16* wf = xf + (size_t)OUT_F * IN_F;
    prep<<<dim3(16384), dim3(256), 0, stream>>>(x, qw, s, xf, wf);

    hipError_t e1 = hipFuncSetAttribute((const void*)gemm_r3,
        hipFuncAttributeMaxDynamicSharedMemorySize, 98304);
    if (e1 == hipSuccess) {
        gemm_r3<<<dim3(256), dim3(512), 98304, stream>>>(xf, wf, out);
        return;
    }
    hipError_t e2 = hipFuncSetAttribute((const void*)gemm8p,
        hipFuncAttributeMaxDynamicSharedMemorySize, 131072);
    if (e2 == hipSuccess)
        gemm8p<<<dim3(256), dim3(512), 131072, stream>>>(xf, wf, out);
    else
        gemm_f16<<<dim3(1024), dim3(256), 0, stream>>>(xf, wf, out);
}

// Round 14
// 135.614 us; speedup vs baseline: 2.4169x; 1.1005x over previous
//
#include <hip/hip_runtime.h>

typedef __attribute__((ext_vector_type(8))) _Float16 f16x8;
typedef __attribute__((ext_vector_type(4))) float    f32x4;
typedef __attribute__((ext_vector_type(4))) int      i32x4;

#define IN_F   4096
#define OUT_F  4096
#define NGRP   32
#define NKT    64          /* K-tiles of 64 */

#define GLOAD16(gsrc, ldst)                                                   \
    __builtin_amdgcn_global_load_lds(                                         \
        (const __attribute__((address_space(1))) unsigned int*)(gsrc),        \
        (__attribute__((address_space(3))) unsigned int*)(ldst), 16, 0, 0)

#define CFENCE  asm volatile("" ::: "memory")
#define BARRIER do { CFENCE; __builtin_amdgcn_s_barrier(); CFENCE; } while (0)
#define VMW6    asm volatile("s_waitcnt vmcnt(6)" ::: "memory")

// ---------------- fused prepass: X fp32->f16 and int4 dequant->f16 ----------
__global__ __launch_bounds__(256)
void prep(const float* __restrict__ X, const int* __restrict__ QW,
          const float* __restrict__ S, _Float16* __restrict__ XF,
          _Float16* __restrict__ WF) {
    if (blockIdx.x < 8192) {
        size_t i = ((size_t)blockIdx.x * 256 + threadIdx.x) * 8;
        f32x4 a = *(const f32x4*)(X + i);
        f32x4 b = *(const f32x4*)(X + i + 4);
        f16x8 h;
        h[0] = (_Float16)a[0]; h[1] = (_Float16)a[1];
        h[2] = (_Float16)a[2]; h[3] = (_Float16)a[3];
        h[4] = (_Float16)b[0]; h[5] = (_Float16)b[1];
        h[6] = (_Float16)b[2]; h[7] = (_Float16)b[3];
        *(f16x8*)(XF + i) = h;
    } else {
        size_t t  = ((size_t)blockIdx.x - 8192) * 256 + threadIdx.x;
        size_t jj = t * 4;                   // int32 index; 2048 per row
        size_t o  = jj >> 11;
        size_t jr = jj & 2047;
        const float s = S[o * NGRP + (jr >> 6)];   // group const across 4 int32
        i32x4 q = *(const i32x4*)(QW + jj);
        f16x8 h;
#pragma unroll
        for (int j = 0; j < 4; ++j) {
            const int v = q[j];
            h[2 * j]     = (_Float16)((float)(((v >> 4) & 15) - 8) * s);
            h[2 * j + 1] = (_Float16)((float)((v & 15) - 8) * s);
        }
        *(f16x8*)(WF + jj * 2) = h;
    }
}

// ---------------- main GEMM: 256^2, BK=64, MERGED phases (2/K-tile) ---------
// Best verified configuration (round 10): 117.5us, MfmaUtil 52.3%, 0 bank
// conflicts. Per K-tile, 2 phases of 2 quadrants (32 MFMA) each; 4 barriers
// per 2 K-tiles. T2 swizzle byte^=(row&7)<<4 realized as pre-swizzled global
// source (linear DMA dest) + swizzled ds_read (rule #21, 128B rows -> fully
// conflict-free). Stage plan: PA: A1(t+1)->b1. PB: A0,B0,B1(t+2)->b0.
// PC: A1(t+2)->b0. PD: A0,B0,B1(t+3)->b1. Every stage >=1 barrier after its
// region's last read. VMW6 at PB/PD ends retires exactly the next buffer's
// 4 stages (8 loads), keeps newest 3 stages (6 loads) in flight; the
// trailing barrier publishes all waves' DMA landings before the reads.
__global__ __launch_bounds__(512, 2)
void gemm8p(const _Float16* __restrict__ A,
            const _Float16* __restrict__ B,
            float*          __restrict__ C)
{
    extern __shared__ char LDSc[];
    char* const ldsA = LDSc;
    char* const ldsB = LDSc + 65536;

    const int tid  = threadIdx.x;
    const int lane = tid & 63;
    const int wid  = tid >> 6;
    const int wm   = wid >> 2;          // 0..1
    const int wn   = wid & 3;           // 0..3

    const int bid = blockIdx.x;         // 256 blocks (16x16 tiles), %8==0
    const int swz = (bid & 7) * 32 + (bid >> 3);
    const int bm0 = (swz >> 4) * 256;
    const int bn0 = (swz & 15) * 256;

    // staging source: thread covers rows r0 and r0+64 of a half-tile,
    // 16 B at swizzled byte-col cs (involution: src-perm == read-perm)
    const int r0 = tid >> 3;                                // 0..63
    const int cs = ((tid & 7) * 16) ^ ((r0 & 7) << 4);      // 0..127
    const _Float16* Asrc = A + (size_t)(bm0 + r0) * IN_F + (cs >> 1);
    const _Float16* Bsrc = B + (size_t)(bn0 + r0) * IN_F + (cs >> 1);
    const int dstoff = wid * 1024;                          // wave-uniform

    // frag-read offsets (swizzled)
    const int lane15 = lane & 15;
    const int swr = (lane & 7) << 4;
    const int c0 = ((lane >> 4) * 16) ^ swr;        // kk=0 byte col
    const int c1 = (64 + (lane >> 4) * 16) ^ swr;   // kk=1
    int rAoff[4], rBoff[2];
#pragma unroll
    for (int mm = 0; mm < 4; ++mm) rAoff[mm] = (wm * 64 + mm * 16 + lane15) * 128;
#pragma unroll
    for (int nn = 0; nn < 2; ++nn) rBoff[nn] = (wn * 32 + nn * 16 + lane15) * 128;

    f16x8 afr[4][2], blo[2][2], bhi[2][2];
    f32x4 acc[8][4];
#pragma unroll
    for (int m = 0; m < 8; ++m)
#pragma unroll
        for (int n = 0; n < 4; ++n) acc[m][n] = (f32x4)0.0f;

#define STAGE_A(HALF, KT, BUF) do {                                           \
        const _Float16* s_ = Asrc + (size_t)(HALF) * 128 * IN_F + (KT) * 64;  \
        char* d_ = ldsA + ((BUF) * 2 + (HALF)) * 16384 + dstoff;              \
        GLOAD16(s_, d_);                                                      \
        GLOAD16(s_ + (size_t)64 * IN_F, d_ + 8192); } while (0)

#define STAGE_B(HALF, KT, BUF) do {                                           \
        const _Float16* s_ = Bsrc + (size_t)(HALF) * 128 * IN_F + (KT) * 64;  \
        char* d_ = ldsB + ((BUF) * 2 + (HALF)) * 16384 + dstoff;              \
        GLOAD16(s_, d_);                                                      \
        GLOAD16(s_ + (size_t)64 * IN_F, d_ + 8192); } while (0)

#define RD_A(BUF, QM) do { char* ab_ = ldsA + ((BUF) * 2 + (QM)) * 16384;     \
        _Pragma("unroll") for (int mm = 0; mm < 4; ++mm) {                    \
            afr[mm][0] = *(const f16x8*)(ab_ + rAoff[mm] + c0);               \
            afr[mm][1] = *(const f16x8*)(ab_ + rAoff[mm] + c1); } } while (0)

#define RD_B(BUF, QN, DST) do { char* bb_ = ldsB + ((BUF) * 2 + (QN)) * 16384;\
        _Pragma("unroll") for (int nn = 0; nn < 2; ++nn) {                    \
            DST[nn][0] = *(const f16x8*)(bb_ + rBoff[nn] + c0);               \
            DST[nn][1] = *(const f16x8*)(bb_ + rBoff[nn] + c1); } } while (0)

#define MFMA_Q(QM, QN, BQ)                                                    \
        __builtin_amdgcn_s_setprio(1);                                        \
        _Pragma("unroll") for (int mm = 0; mm < 4; ++mm)                      \
        _Pragma("unroll") for (int nn = 0; nn < 2; ++nn)                      \
        _Pragma("unroll") for (int kk = 0; kk < 2; ++kk)                      \
            acc[(QM)*4+mm][(QN)*2+nn] =                                       \
                __builtin_amdgcn_mfma_f32_16x16x32_f16(                       \
                    afr[mm][kk], BQ[nn][kk], acc[(QM)*4+mm][(QN)*2+nn],0,0,0);\
        __builtin_amdgcn_s_setprio(0);

    // prologue: K0 full -> buf0, K1 {A0,B0,B1} -> buf1 (7 stages, 14 loads).
    STAGE_A(0, 0, 0); STAGE_B(0, 0, 0); STAGE_B(1, 0, 0); STAGE_A(1, 0, 0);
    STAGE_A(0, 1, 1); STAGE_B(0, 1, 1); STAGE_B(1, 1, 1);
    VMW6; BARRIER;

    for (int t = 0; t < NKT; t += 2) {
        const int k2 = (t + 2) & 63;   // t=62 -> dead restage of K0/K1
        const int k3 = (t + 3) & 63;
        // ---- PA: quadrants Q00,Q01 of K-tile t (buf0) ----
        RD_A(0, 0); RD_B(0, 0, blo); RD_B(0, 1, bhi);
        STAGE_A(1, t + 1, 1);
        MFMA_Q(0, 0, blo); MFMA_Q(0, 1, bhi);
        BARRIER;
        // ---- PB: quadrants Q10,Q11 (buf0) ; stage t+2 A0/B0/B1 -> b0 ----
        RD_A(0, 1);
        STAGE_A(0, k2, 0); STAGE_B(0, k2, 0); STAGE_B(1, k2, 0);
        MFMA_Q(1, 0, blo); MFMA_Q(1, 1, bhi);
        VMW6; BARRIER;      // retires buf1 K-tile t+1; barrier publishes
        // ---- PC: quadrants Q00,Q01 of K-tile t+1 (buf1) ----
        RD_A(1, 0); RD_B(1, 0, blo); RD_B(1, 1, bhi);
        STAGE_A(1, k2, 0);
        MFMA_Q(0, 0, blo); MFMA_Q(0, 1, bhi);
        BARRIER;
        // ---- PD: quadrants Q10,Q11 (buf1) ; stage t+3 A0/B0/B1 -> b1 ----
        RD_A(1, 1);
        STAGE_A(0, k3, 1); STAGE_B(0, k3, 1); STAGE_B(1, k3, 1);
        MFMA_Q(1, 0, blo); MFMA_Q(1, 1, bhi);
        VMW6; BARRIER;      // retires buf0 K-tile t+2
    }
    asm volatile("s_waitcnt vmcnt(0)" ::: "memory");   // drain DMA before end

#pragma unroll
    for (int m = 0; m < 8; ++m) {
        const int Mr = bm0 + (m >> 2) * 128 + wm * 64 + (m & 3) * 16 + (lane >> 4) * 4;
#pragma unroll
        for (int n = 0; n < 4; ++n) {
            const int Nc = bn0 + (n >> 1) * 128 + wn * 32 + (n & 1) * 16 + lane15;
#pragma unroll
            for (int r = 0; r < 4; ++r)
                C[(size_t)(Mr + r) * OUT_F + Nc] = acc[m][n][r];
        }
    }
#undef STAGE_A
#undef STAGE_B
#undef RD_A
#undef RD_B
#undef MFMA_Q
}

// ---------------- fallback: m97-structure GEMM (static 16 KB LDS) ----------
__global__ __launch_bounds__(256, 3)
void gemm_f16(const _Float16* __restrict__ A,
              const _Float16* __restrict__ B,
              float*          __restrict__ C)
{
    __shared__ __align__(16) _Float16 lA[128 * 32];
    __shared__ __align__(16) _Float16 lB[128 * 32];

    const int tid  = threadIdx.x;
    const int lane = tid & 63;
    const int bid = blockIdx.x;
    const int swz = (bid & 7) * 128 + (bid >> 3);
    const int bm0 = (swz >> 5) * 128;
    const int bn0 = (swz & 31) * 128;

    const int sr = tid >> 2;
    const int sc = (tid & 3) * 8;
    const _Float16* Aps = A + (size_t)(bm0 + sr) * IN_F + sc;
    const _Float16* Bps = B + (size_t)(bn0 + sr) * IN_F + sc;
    char* lAb = (char*)lA + (tid & ~63) * 16;
    char* lBb = (char*)lB + (tid & ~63) * 16;

    const int wv = tid >> 6;
    const int wr = (wv >> 1) * 64;
    const int wc = (wv & 1)  * 64;
    const int lr  = lane & 15;
    const int lkb = (lane >> 4) * 16;

    f32x4 acc[4][4];
#pragma unroll
    for (int m = 0; m < 4; ++m)
#pragma unroll
        for (int n = 0; n < 4; ++n) acc[m][n] = (f32x4)0.0f;

    for (int kt = 0; kt < 128; ++kt) {
        __syncthreads();
        {
            const _Float16* ak = Aps + kt * 32;
            const _Float16* bk = Bps + kt * 32;
            GLOAD16(ak, lAb);
            GLOAD16(ak + (size_t)64 * IN_F, lAb + 4096);
            GLOAD16(bk, lBb);
            GLOAD16(bk + (size_t)64 * IN_F, lBb + 4096);
        }
        __syncthreads();

        f16x8 a[4], b[4];
#pragma unroll
        for (int m = 0; m < 4; ++m)
            a[m] = *(const f16x8*)((const char*)lA + (wr + m * 16 + lr) * 64 + lkb);
#pragma unroll
        for (int n = 0; n < 4; ++n)
            b[n] = *(const f16x8*)((const char*)lB + (wc + n * 16 + lr) * 64 + lkb);
#pragma unroll
        for (int m = 0; m < 4; ++m)
#pragma unroll
            for (int n = 0; n < 4; ++n)
                acc[m][n] = __builtin_amdgcn_mfma_f32_16x16x32_f16(
                    a[m], b[n], acc[m][n], 0, 0, 0);
    }

    const int crow = bm0 + wr + (lane >> 4) * 4;
    const int ccol = bn0 + wc + lr;
#pragma unroll
    for (int m = 0; m < 4; ++m)
#pragma unroll
        for (int n = 0; n < 4; ++n)
#pragma unroll
            for (int r = 0; r < 4; ++r)
                C[(size_t)(crow + m * 16 + r) * OUT_F + (ccol + n * 16)]
                    = acc[m][n][r];
}

extern "C" void kernel_launch(void* const* d_in, const int* in_sizes, int n_in,
                              void* d_out, int out_size, void* d_ws, size_t ws_size,
                              hipStream_t stream) {
    (void)in_sizes; (void)n_in; (void)out_size; (void)ws_size;
    const float* x  = (const float*)d_in[0];
    const int*   qw = (const int*)d_in[1];
    const float* s  = (const float*)d_in[2];
    float*       out = (float*)d_out;

    _Float16* xf = (_Float16*)d_ws;
    _Float16* wf = xf + (size_t)OUT_F * IN_F;
    prep<<<dim3(16384), dim3(256), 0, stream>>>(x, qw, s, xf, wf);

    hipError_t e = hipFuncSetAttribute((const void*)gemm8p,
        hipFuncAttributeMaxDynamicSharedMemorySize, 131072);
    if (e == hipSuccess)
        gemm8p<<<dim3(256), dim3(512), 131072, stream>>>(xf, wf, out);
    else
        gemm_f16<<<dim3(1024), dim3(256), 0, stream>>>(xf, wf, out);
}